// Round 3
// baseline (99.827 us; speedup 1.0000x reference)
//
#include <hip/hip_runtime.h>

typedef float f32x4 __attribute__((ext_vector_type(4)));
typedef short s16x8 __attribute__((ext_vector_type(8)));

#define B_SZ   4096
#define C_N    64
#define D_K    512
#define H_N    1024
#define HT     16       // h-blocks per company (64 h each)
#define HB     64       // h per block (4 waves x 16)
#define SCHUNK 32       // samples per chunk (2 M-frags of 16)
#define KSTEPS 16       // 512 / 32
#define MAXCH  192      // 64 + 4096/32
#define NWG    (MAXCH * HT)   // 3072, divisible by 8

__device__ __forceinline__ short f2bf(float f){
  unsigned u = __float_as_uint(f);
  u += 0x7FFFu + ((u >> 16) & 1u);   // RTNE
  return (short)(u >> 16);
}

// A&S 7.1.26, |err| <= 1.5e-7 — ~12 VALU ops vs libm erff's ~30+
__device__ __forceinline__ float erf_fast(float x){
  float ax = fabsf(x);
  float t = __builtin_amdgcn_rcpf(1.0f + 0.3275911f * ax);
  float p = t * (0.254829592f + t * (-0.284496736f + t * (1.421413741f +
            t * (-1.453152027f + t * 1.061405429f))));
  float r = 1.0f - p * __expf(-ax * ax);
  return copysignf(r, x);
}
__device__ __forceinline__ float gelu_exact(float x){
  return 0.5f * x * (1.0f + erf_fast(x * 0.70710678118654752f));
}

__global__ void k_count(const int* __restrict__ cid, int* __restrict__ counts){
  int i = blockIdx.x * 256 + threadIdx.x;
  if (i < B_SZ) atomicAdd(&counts[cid[i]], 1);
}

__global__ void k_scan(const int* __restrict__ counts, int* __restrict__ offsets,
                       int* __restrict__ cursor, int* __restrict__ chunk_table,
                       int* __restrict__ nchunks){
  int l = threadIdx.x;              // 64 threads = 1 wave
  int v = counts[l];
  int x = v;
  #pragma unroll
  for (int d = 1; d < 64; d <<= 1){
    int y = __shfl_up(x, d, 64);
    if (l >= d) x += y;
  }
  offsets[l] = x - v;
  cursor[l]  = x - v;
  if (l == 63) offsets[64] = x;
  // chunk table: one entry per (company, chunk-within-company)
  int nch = (v + SCHUNK - 1) / SCHUNK;
  int cx = nch;
  #pragma unroll
  for (int d = 1; d < 64; d <<= 1){
    int y = __shfl_up(cx, d, 64);
    if (l >= d) cx += y;
  }
  int cbase = cx - nch;
  for (int j = 0; j < nch; ++j) chunk_table[cbase + j] = (l << 8) | j;
  if (l == 63) nchunks[0] = cx;
}

__global__ void k_scatter(const int* __restrict__ cid, const float* __restrict__ b2,
                          int* __restrict__ cursor, int* __restrict__ bucket,
                          float* __restrict__ out){
  int i = blockIdx.x * 256 + threadIdx.x;
  if (i < B_SZ){
    int c = cid[i];
    int pos = atomicAdd(&cursor[c], 1);
    bucket[pos] = i;
    out[i] = b2[c];                 // initialize output with bias2
  }
}

__global__ __launch_bounds__(256, 5) void k_main(
    const float* __restrict__ z, const float* __restrict__ W1,
    const float* __restrict__ b1, const float* __restrict__ W2,
    const int* __restrict__ offsets, const int* __restrict__ bucket,
    const int* __restrict__ chunk_table, const int* __restrict__ nchunks,
    float* __restrict__ out)
{
  __shared__ s16x8 A_lds[SCHUNK * D_K / 8];   // 32 KiB, frag-ordered bf16

  // XCD-balanced mapping: XCD = flat%8 gets chunks {x, x+8, x+16, ...};
  // all 16 ht-blocks of a chunk land on the same XCD (z L2 reuse).
  const int flat = blockIdx.x;
  const int x = flat & 7;
  const int o = flat >> 3;
  const int g  = x + (o >> 4) * 8;   // chunk id
  const int ht = o & 15;
  if (g >= nchunks[0]) return;
  const int entry = chunk_table[g];
  const int c = entry >> 8, j = entry & 255;
  const int base_slot = offsets[c] + j * SCHUNK;
  const int end_c = offsets[c + 1];

  const int tid  = threadIdx.x;
  const int lane = tid & 63, wave = tid >> 6;      // 4 waves
  const int l15 = lane & 15, l4 = lane >> 4;
  const int h0 = ht * HB + wave * 16;              // 16 h per wave
  const float* Wc = W1 + (size_t)c * D_K * H_N;
  const float* bp_base = Wc + (size_t)(l4 * 8) * H_N + h0 + l15;

  // ---- issue entire W1 prologue pipeline FIRST (overlaps A-staging latency) ----
  float fb[4][8];                     // 4 slots x 8 k-elems, fully unrolled -> regs
  #pragma unroll
  for (int s = 0; s < 4; ++s){
    #pragma unroll
    for (int e = 0; e < 8; ++e)
      fb[s][e] = bp_base[(size_t)(s * 32 + e) * H_N];
  }

  const int h_a = c * H_N + h0 + l15;
  const float b1v = b1[h_a];
  const float w2v = W2[h_a];

  // ---- stage 32 sample rows x 512 K as bf16, MFMA-frag order ----
  #pragma unroll
  for (int i = 0; i < 8; ++i){
    int unit  = tid + 256 * i;          // 0..2047; contiguous LDS write
    int row16 = unit & 15;
    int koff  = (unit >> 4) & 3;
    int ks    = (unit >> 6) & 15;
    int m     = unit >> 10;             // 0..1
    int r     = m * 16 + row16;
    int koct  = ks * 4 + koff;          // k = koct*8 .. koct*8+7
    int slot  = base_slot + r;
    float4 a = make_float4(0.f,0.f,0.f,0.f), b = make_float4(0.f,0.f,0.f,0.f);
    if (slot < end_c){
      const float* zp = z + (size_t)bucket[slot] * D_K + koct * 8;
      a = *(const float4*)zp;
      b = *(const float4*)(zp + 4);
    }
    s16x8 v;
    v[0]=f2bf(a.x); v[1]=f2bf(a.y); v[2]=f2bf(a.z); v[3]=f2bf(a.w);
    v[4]=f2bf(b.x); v[5]=f2bf(b.y); v[6]=f2bf(b.z); v[7]=f2bf(b.w);
    A_lds[unit] = v;
  }
  __syncthreads();

  // ---- K loop: rolling 4-deep W1 prefetch, 2 MFMA per kstep ----
  f32x4 acc0 = 0, acc1 = 0;
  #pragma unroll
  for (int ks = 0; ks < KSTEPS; ++ks){
    const int sl = ks & 3;
    s16x8 bf;
    #pragma unroll
    for (int e = 0; e < 8; ++e) bf[e] = f2bf(fb[sl][e]);
    s16x8 af0 = A_lds[(ks     ) * 64 + lane];
    s16x8 af1 = A_lds[(16 + ks) * 64 + lane];
    acc0 = __builtin_amdgcn_mfma_f32_16x16x32_bf16(af0, bf, acc0, 0, 0, 0);
    acc1 = __builtin_amdgcn_mfma_f32_16x16x32_bf16(af1, bf, acc1, 0, 0, 0);
    if (ks < KSTEPS - 4){
      #pragma unroll
      for (int e = 0; e < 8; ++e)
        fb[sl][e] = bp_base[(size_t)((ks + 4) * 32 + e) * H_N];
    }
  }

  // ---- epilogue: GELU(acc + b1) * W2, 16-lane reduce, atomic to out ----
  #pragma unroll
  for (int m = 0; m < 2; ++m){
    f32x4 accm = m ? acc1 : acc0;
    #pragma unroll
    for (int r = 0; r < 4; ++r){
      float s = gelu_exact(accm[r] + b1v) * w2v;
      s += __shfl_xor(s, 1, 64);
      s += __shfl_xor(s, 2, 64);
      s += __shfl_xor(s, 4, 64);
      s += __shfl_xor(s, 8, 64);
      int slot = base_slot + m * 16 + l4 * 4 + r;
      if (l15 == 0 && slot < end_c){
        atomicAdd(&out[bucket[slot]], s);
      }
    }
  }
}

extern "C" void kernel_launch(void* const* d_in, const int* in_sizes, int n_in,
                              void* d_out, int out_size, void* d_ws, size_t ws_size,
                              hipStream_t stream){
  const float* z  = (const float*)d_in[0];
  const int*   cid= (const int*)  d_in[1];
  const float* W1 = (const float*)d_in[2];
  const float* b1 = (const float*)d_in[3];
  const float* W2 = (const float*)d_in[4];
  const float* b2 = (const float*)d_in[5];
  float* out = (float*)d_out;

  int* ws          = (int*)d_ws;
  int* counts      = ws;          // [64]
  int* offsets     = ws + 64;     // [65]
  int* cursor      = ws + 192;    // [64]
  int* chunk_table = ws + 256;    // [192]
  int* nchunks     = ws + 448;    // [1]
  int* bucket      = ws + 512;    // [4096]

  hipMemsetAsync(counts, 0, 64 * sizeof(int), stream);
  k_count  <<<(B_SZ + 255) / 256, 256, 0, stream>>>(cid, counts);
  k_scan   <<<1, 64, 0, stream>>>(counts, offsets, cursor, chunk_table, nchunks);
  k_scatter<<<(B_SZ + 255) / 256, 256, 0, stream>>>(cid, b2, cursor, bucket, out);
  k_main   <<<NWG, 256, 0, stream>>>(z, W1, b1, W2, offsets, bucket,
                                     chunk_table, nchunks, out);
}

// Round 4
// 76.374 us; speedup vs baseline: 1.3071x; 1.3071x over previous
//
#include <hip/hip_runtime.h>

typedef float f32x4 __attribute__((ext_vector_type(4)));
typedef short s16x8 __attribute__((ext_vector_type(8)));

#define B_SZ 4096
#define C_N  64
#define D_K  512
#define H_N  1024
#define HQ   4              // h-quarters of 256 per company
#define ROWS 80             // sample rows per pass (5 m-frags)
#define MF   5
#define KT   16             // k-tiles of 32
#define BT_F32 (32 * 256)   // 8192 f32 = 32 KB per B buffer
#define LDS_BYTES (80*1024 + 2*32*1024)   // 144 KB

__device__ __forceinline__ short f2bf(float f){
  unsigned u = __float_as_uint(f);
  u += 0x7FFFu + ((u >> 16) & 1u);   // RTNE
  return (short)(u >> 16);
}
// A&S 7.1.26, |err| <= 1.5e-7
__device__ __forceinline__ float erf_fast(float x){
  float ax = fabsf(x);
  float t = __builtin_amdgcn_rcpf(1.0f + 0.3275911f * ax);
  float p = t * (0.254829592f + t * (-0.284496736f + t * (1.421413741f +
            t * (-1.453152027f + t * 1.061405429f))));
  float r = 1.0f - p * __expf(-ax * ax);
  return copysignf(r, x);
}
__device__ __forceinline__ float gelu_exact(float x){
  return 0.5f * x * (1.0f + erf_fast(x * 0.70710678118654752f));
}

// Fused count + scan + scatter + out-init. One block of 256.
__global__ void k_prep(const int* __restrict__ cid, const float* __restrict__ b2,
                       int* __restrict__ offsets, int* __restrict__ bucket,
                       float* __restrict__ out){
  __shared__ int hist[C_N];
  const int tid = threadIdx.x;
  if (tid < C_N) hist[tid] = 0;
  __syncthreads();
  for (int i = tid; i < B_SZ; i += 256) atomicAdd(&hist[cid[i]], 1);
  __syncthreads();
  if (tid < 64){
    int v = hist[tid];
    int x = v;
    #pragma unroll
    for (int d = 1; d < 64; d <<= 1){
      int y = __shfl_up(x, d, 64);
      if (tid >= d) x += y;
    }
    offsets[tid] = x - v;
    if (tid == 63) offsets[64] = x;
    hist[tid] = x - v;                 // reuse as cursor
  }
  __syncthreads();
  for (int i = tid; i < B_SZ; i += 256){
    int c = cid[i];
    int p = atomicAdd(&hist[c], 1);
    bucket[p] = i;
    out[i] = b2[c];
  }
}

__global__ __launch_bounds__(512) void k_main(
    const float* __restrict__ z, const float* __restrict__ W1,
    const float* __restrict__ b1, const float* __restrict__ W2,
    const int* __restrict__ offsets, const int* __restrict__ bucket,
    float* __restrict__ out)
{
  extern __shared__ char smem[];
  s16x8* A_lds = (s16x8*)smem;                 // 80 KB, frag-ordered z (bf16)
  float* B_lds = (float*)(smem + 80 * 1024);   // 2 x 32 KB W1 tiles (f32)

  const int c  = blockIdx.x >> 2;
  const int hq = blockIdx.x & 3;
  const int off_c = offsets[c], end_c = offsets[c + 1];
  const int n_c = end_c - off_c;
  if (n_c == 0) return;

  const int tid  = threadIdx.x;
  const int lane = tid & 63, wave = tid >> 6;    // 8 waves
  const int l15 = lane & 15, l4 = lane >> 4;
  const float* Wc = W1 + (size_t)c * D_K * H_N + hq * 256;
  const int sidx0 = wave * 1024 + lane * 4;      // f32 idx into B tile (+s*256)

  const int hcol = c * H_N + hq * 256 + wave * 32 + l15;
  const float b1v0 = b1[hcol], b1v1 = b1[hcol + 16];
  const float w2v0 = W2[hcol], w2v1 = W2[hcol + 16];

  // stage one [32k x 256h] W1 tile via direct-to-LDS 16B loads (1KB runs/wave)
  auto stage = [&](int buf, int t){
    float* dbase = B_lds + buf * BT_F32;
    #pragma unroll
    for (int s = 0; s < 4; ++s){
      int idx = sidx0 + s * 256;
      int row = idx >> 8, col = idx & 255;
      const float* src = Wc + (size_t)(t * 32 + row) * H_N + col;
      __builtin_amdgcn_global_load_lds(
        (const __attribute__((address_space(1))) void*)src,
        (__attribute__((address_space(3))) void*)(dbase + idx), 16, 0, 0);
    }
  };

  for (int rb = 0; rb < n_c; rb += ROWS){
    const int rows = (n_c - rb < ROWS) ? (n_c - rb) : ROWS;
    const int M = (rows + 15) >> 4;

    __syncthreads();   // protect A_lds/B_lds from previous pass readers
    // ---- stage A: up to 80 z-rows as bf16 in MFMA-frag order ----
    #pragma unroll
    for (int i = 0; i < 10; ++i){
      int unit = tid + 512 * i;
      if (unit >= M * 1024) break;
      int l2 = unit & 63, ks = (unit >> 6) & 15, m = unit >> 10;
      int rg = rb + m * 16 + (l2 & 15);
      int k  = ks * 32 + (l2 >> 4) * 8;
      float4 a = make_float4(0.f,0.f,0.f,0.f), b = make_float4(0.f,0.f,0.f,0.f);
      if (rg < n_c){
        const float* zp = z + (size_t)bucket[off_c + rg] * D_K + k;
        a = *(const float4*)zp;
        b = *(const float4*)(zp + 4);
      }
      s16x8 v;
      v[0]=f2bf(a.x); v[1]=f2bf(a.y); v[2]=f2bf(a.z); v[3]=f2bf(a.w);
      v[4]=f2bf(b.x); v[5]=f2bf(b.y); v[6]=f2bf(b.z); v[7]=f2bf(b.w);
      A_lds[unit] = v;
    }
    stage(0, 0);       // prologue tile
    __syncthreads();   // drains vmcnt+lgkmcnt: A and tile 0 visible

    f32x4 acc[MF][2];
    #pragma unroll
    for (int m = 0; m < MF; ++m){ acc[m][0] = 0; acc[m][1] = 0; }

    for (int t = 0; t < KT; ++t){
      if (t + 1 < KT){
        stage((t + 1) & 1, t + 1);
        asm volatile("s_waitcnt vmcnt(4)" ::: "memory");  // tile t done, t+1 in flight
      } else {
        asm volatile("s_waitcnt vmcnt(0)" ::: "memory");
      }
      __builtin_amdgcn_s_barrier();
      const float* Bt = B_lds + (t & 1) * BT_F32;
      s16x8 bf0, bf1;
      #pragma unroll
      for (int e = 0; e < 8; ++e){
        int r0 = (l4 * 8 + e) * 256 + wave * 32 + l15;
        bf0[e] = f2bf(Bt[r0]);
        bf1[e] = f2bf(Bt[r0 + 16]);
      }
      #pragma unroll
      for (int m = 0; m < MF; ++m){
        if (m >= M) break;
        s16x8 af = A_lds[(m * 16 + t) * 64 + lane];
        acc[m][0] = __builtin_amdgcn_mfma_f32_16x16x32_bf16(af, bf0, acc[m][0], 0, 0, 0);
        acc[m][1] = __builtin_amdgcn_mfma_f32_16x16x32_bf16(af, bf1, acc[m][1], 0, 0, 0);
      }
      __builtin_amdgcn_s_barrier();
    }

    // ---- epilogue: GELU + W2 dot over this block's 32h/wave, atomic add ----
    #pragma unroll
    for (int m = 0; m < MF; ++m){
      if (m >= M) break;
      #pragma unroll
      for (int r = 0; r < 4; ++r){
        float s = gelu_exact(acc[m][0][r] + b1v0) * w2v0
                + gelu_exact(acc[m][1][r] + b1v1) * w2v1;
        s += __shfl_xor(s, 1, 64);
        s += __shfl_xor(s, 2, 64);
        s += __shfl_xor(s, 4, 64);
        s += __shfl_xor(s, 8, 64);
        int rg = rb + m * 16 + l4 * 4 + r;
        if (l15 == 0 && rg < n_c){
          atomicAdd(&out[bucket[off_c + rg]], s);
        }
      }
    }
  }
}

extern "C" void kernel_launch(void* const* d_in, const int* in_sizes, int n_in,
                              void* d_out, int out_size, void* d_ws, size_t ws_size,
                              hipStream_t stream){
  const float* z  = (const float*)d_in[0];
  const int*   cid= (const int*)  d_in[1];
  const float* W1 = (const float*)d_in[2];
  const float* b1 = (const float*)d_in[3];
  const float* W2 = (const float*)d_in[4];
  const float* b2 = (const float*)d_in[5];
  float* out = (float*)d_out;

  int* ws      = (int*)d_ws;
  int* offsets = ws;           // [65]
  int* bucket  = ws + 128;     // [4096]

  static bool attr_set = false;
  (void)hipFuncSetAttribute((const void*)k_main,
                            hipFuncAttributeMaxDynamicSharedMemorySize, LDS_BYTES);

  k_prep<<<1, 256, 0, stream>>>(cid, b2, offsets, bucket, out);
  k_main<<<C_N * HQ, 512, LDS_BYTES, stream>>>(z, W1, b1, W2, offsets, bucket, out);
}

// Round 5
// 52.310 us; speedup vs baseline: 1.9084x; 1.4600x over previous
//
#include <hip/hip_runtime.h>

typedef float f32x4 __attribute__((ext_vector_type(4)));
typedef short s16x8 __attribute__((ext_vector_type(8)));

#define B_SZ 4096
#define C_N  64
#define D_K  512
#define H_N  1024
#define HS   4               // h-slices of 256 per company
#define MAXR 112             // sample rows per pass (7 m-frags)
#define MF   7
#define KSTEPS 16            // 512 / 32
#define DEPTH 8              // register prefetch depth (k-steps)
#define LDS_BYTES (MAXR*D_K*2 + 512)   // 112 KB A + partial array

__device__ __forceinline__ short f2bf(float f){
  unsigned u = __float_as_uint(f);
  u += 0x7FFFu + ((u >> 16) & 1u);   // RTNE
  return (short)(u >> 16);
}
// A&S 7.1.26, |err| <= 1.5e-7
__device__ __forceinline__ float erf_fast(float x){
  float ax = fabsf(x);
  float t = __builtin_amdgcn_rcpf(1.0f + 0.3275911f * ax);
  float p = t * (0.254829592f + t * (-0.284496736f + t * (1.421413741f +
            t * (-1.453152027f + t * 1.061405429f))));
  float r = 1.0f - p * __expf(-ax * ax);
  return copysignf(r, x);
}
__device__ __forceinline__ float gelu_exact(float x){
  return 0.5f * x * (1.0f + erf_fast(x * 0.70710678118654752f));
}

// Fused count + scan + scatter + out-init. One block of 1024.
__global__ void k_prep(const int* __restrict__ cid, const float* __restrict__ b2,
                       int* __restrict__ offsets, int* __restrict__ bucket,
                       float* __restrict__ out){
  __shared__ int hist[C_N];
  const int tid = threadIdx.x;
  if (tid < C_N) hist[tid] = 0;
  __syncthreads();
  for (int i = tid; i < B_SZ; i += 1024) atomicAdd(&hist[cid[i]], 1);
  __syncthreads();
  if (tid < 64){                        // wave 0 scans
    int v = hist[tid];
    int x = v;
    #pragma unroll
    for (int d = 1; d < 64; d <<= 1){
      int y = __shfl_up(x, d, 64);
      if (tid >= d) x += y;
    }
    offsets[tid] = x - v;
    if (tid == 63) offsets[64] = x;
    hist[tid] = x - v;                  // reuse as cursor
  }
  __syncthreads();
  for (int i = tid; i < B_SZ; i += 1024){
    int c = cid[i];
    int p = atomicAdd(&hist[c], 1);
    bucket[p] = i;
    out[i] = b2[c];
  }
}

__global__ __launch_bounds__(1024, 4) void k_main(
    const float* __restrict__ z, const float* __restrict__ W1,
    const float* __restrict__ b1, const float* __restrict__ W2,
    const int* __restrict__ offsets, const int* __restrict__ bucket,
    float* __restrict__ out)
{
  extern __shared__ char smem[];
  s16x8* A_lds   = (s16x8*)smem;                     // 112 KB frag-ordered z (bf16)
  float* partial = (float*)(smem + MAXR * D_K * 2);  // [128] per-row partials

  // flat = hs*64 + c  ->  flat%8 = c%8: a company's 4 blocks + its z stay on one XCD
  const int flat = blockIdx.x;
  const int c  = flat & 63;
  const int hs = flat >> 6;
  const int off_c = offsets[c];
  const int n_c   = offsets[c + 1] - off_c;
  if (n_c == 0) return;

  const int tid  = threadIdx.x;
  const int lane = tid & 63, wave = tid >> 6;        // 16 waves
  const int l15 = lane & 15, l4 = lane >> 4;
  const int h0 = hs * 256 + wave * 16;               // 16 h per wave
  const float* Wc = W1 + (size_t)c * D_K * H_N;
  const float* bp_base = Wc + (size_t)(l4 * 8) * H_N + h0 + l15;

  const int hcol = c * H_N + h0 + l15;
  const float b1v = b1[hcol];
  const float w2v = W2[hcol];

  for (int rb = 0; rb < n_c; rb += MAXR){
    const int rows = (n_c - rb < MAXR) ? (n_c - rb) : MAXR;
    const int M = (rows + 15) >> 4;

    __syncthreads();   // prev pass done with partial[] and A_lds

    // ---- issue W1 prologue: DEPTH k-steps x 8 elems, independent loads ----
    float fb[DEPTH][8];
    #pragma unroll
    for (int s = 0; s < DEPTH; ++s){
      #pragma unroll
      for (int e = 0; e < 8; ++e)
        fb[s][e] = bp_base[(size_t)(s * 32 + e) * H_N];
    }

    if (tid < 128) partial[tid] = 0.0f;

    // ---- stage A: rows x 512 k as bf16, MFMA-frag order (iter i == m-frag i) ----
    for (int i = 0; i < M; ++i){
      int unit = tid + 1024 * i;
      int rg = rb + i * 16 + l15;
      int k  = wave * 32 + l4 * 8;
      float4 a = make_float4(0.f,0.f,0.f,0.f), b = make_float4(0.f,0.f,0.f,0.f);
      if (rg < n_c){
        const float* zp = z + (size_t)bucket[off_c + rg] * D_K + k;
        a = *(const float4*)zp;
        b = *(const float4*)(zp + 4);
      }
      s16x8 v;
      v[0]=f2bf(a.x); v[1]=f2bf(a.y); v[2]=f2bf(a.z); v[3]=f2bf(a.w);
      v[4]=f2bf(b.x); v[5]=f2bf(b.y); v[6]=f2bf(b.z); v[7]=f2bf(b.w);
      A_lds[unit] = v;
    }
    __syncthreads();   // A visible to all waves; last barrier until epilogue

    f32x4 acc[MF];
    #pragma unroll
    for (int m = 0; m < MF; ++m) acc[m] = 0;

    // ---- barrier-free K loop: 8-deep rolling register prefetch ----
    #pragma unroll
    for (int t = 0; t < KSTEPS; ++t){
      const int sl = t & (DEPTH - 1);
      s16x8 bf;
      #pragma unroll
      for (int e = 0; e < 8; ++e) bf[e] = f2bf(fb[sl][e]);
      #pragma unroll
      for (int m = 0; m < MF; ++m){
        if (m >= M) break;
        s16x8 af = A_lds[(m * 16 + t) * 64 + lane];
        acc[m] = __builtin_amdgcn_mfma_f32_16x16x32_bf16(af, bf, acc[m], 0, 0, 0);
      }
      if (t < KSTEPS - DEPTH){
        #pragma unroll
        for (int e = 0; e < 8; ++e)
          fb[sl][e] = bp_base[(size_t)((t + DEPTH) * 32 + e) * H_N];
      }
    }

    // ---- epilogue: GELU + W2, 16-lane reduce, LDS partial, then global atomic ----
    #pragma unroll
    for (int m = 0; m < MF; ++m){
      if (m >= M) break;
      #pragma unroll
      for (int r = 0; r < 4; ++r){
        float s = gelu_exact(acc[m][r] + b1v) * w2v;
        s += __shfl_xor(s, 1, 64);
        s += __shfl_xor(s, 2, 64);
        s += __shfl_xor(s, 4, 64);
        s += __shfl_xor(s, 8, 64);
        int row = m * 16 + l4 * 4 + r;
        if (l15 == 0 && row < rows){
          atomicAdd(&partial[row], s);   // LDS atomic, 16 waves converge here
        }
      }
    }
    __syncthreads();
    for (int r = tid; r < rows; r += 1024){
      atomicAdd(&out[bucket[off_c + rb + r]], partial[r]);
    }
  }
}

extern "C" void kernel_launch(void* const* d_in, const int* in_sizes, int n_in,
                              void* d_out, int out_size, void* d_ws, size_t ws_size,
                              hipStream_t stream){
  const float* z  = (const float*)d_in[0];
  const int*   cid= (const int*)  d_in[1];
  const float* W1 = (const float*)d_in[2];
  const float* b1 = (const float*)d_in[3];
  const float* W2 = (const float*)d_in[4];
  const float* b2 = (const float*)d_in[5];
  float* out = (float*)d_out;

  int* ws      = (int*)d_ws;
  int* offsets = ws;           // [65]
  int* bucket  = ws + 128;     // [4096]

  (void)hipFuncSetAttribute((const void*)k_main,
                            hipFuncAttributeMaxDynamicSharedMemorySize, LDS_BYTES);

  k_prep<<<1, 1024, 0, stream>>>(cid, b2, offsets, bucket, out);
  k_main<<<C_N * HS, 1024, LDS_BYTES, stream>>>(z, W1, b1, W2, offsets, bucket, out);
}